// Round 10
// baseline (316.859 us; speedup 1.0000x reference)
//
#include <hip/hip_runtime.h>
#include <stdint.h>

typedef __bf16 bf16;
typedef __bf16 bfx8 __attribute__((ext_vector_type(8)));
typedef __bf16 bfx4 __attribute__((ext_vector_type(4)));
typedef float floatx4 __attribute__((ext_vector_type(4)));

#define B_ 2
#define S_ 2048
#define DIM_ 2048
#define H_ 16
#define DK_ 128
#define DR_ 64
#define DC_ 512
#define DCP_ 1024
#define DV_ 128
#define DQK_ 192

#define MASK_VAL (-30000.0f)
#define C1_ 0.10411754f   // (1/sqrt(192)) * log2(e), folded into q at G2

// ----------------------------------------------------------------------------
// k_prep: fused x-cast (blocks 0..4095) + all-7-weights transpose+downcast
// (blocks 4096..12415). One launch instead of two.
// ----------------------------------------------------------------------------
__global__ void k_prep(
    const float* __restrict__ x, bf16* __restrict__ xb,
    const float* __restrict__ W_c, const float* __restrict__ W_cp,
    const float* __restrict__ W_qc, const float* __restrict__ W_qr,
    const float* __restrict__ W_kc, const float* __restrict__ W_kr,
    const float* __restrict__ W_v,
    bf16* __restrict__ Wt_c, bf16* __restrict__ Wt_cp,
    bf16* __restrict__ Wt_qc, bf16* __restrict__ Wt_qr,
    bf16* __restrict__ Wt_kc, bf16* __restrict__ Wt_kr,
    bf16* __restrict__ Wt_v) {
    __shared__ float tile[32][33];
    int bid0 = blockIdx.x;
    if (bid0 < 4096) {   // cast: 8.4M elems / 8 per thread
        size_t i = ((size_t)bid0 * 256 + threadIdx.x) * 8;
        float4 a = *(const float4*)(x + i);
        float4 b = *(const float4*)(x + i + 4);
        bfx8 r;
        r[0] = (bf16)a.x; r[1] = (bf16)a.y; r[2] = (bf16)a.z; r[3] = (bf16)a.w;
        r[4] = (bf16)b.x; r[5] = (bf16)b.y; r[6] = (bf16)b.z; r[7] = (bf16)b.w;
        *(bfx8*)(xb + i) = r;
        return;
    }
    int bid = bid0 - 4096;
    const float* in; bf16* out; int K, N, lx, ly, local;
    if (bid < 1024)      { in = W_c;  out = Wt_c;  K = 2048; N = 512;  lx = 4; ly = 6; local = bid; }
    else if (bid < 3072) { in = W_cp; out = Wt_cp; K = 2048; N = 1024; lx = 5; ly = 6; local = bid - 1024; }
    else if (bid < 5120) { in = W_qc; out = Wt_qc; K = 1024; N = 128;  lx = 2; ly = 5; local = bid - 3072; }
    else if (bid < 6144) { in = W_qr; out = Wt_qr; K = 1024; N = 64;   lx = 1; ly = 5; local = bid - 5120; }
    else if (bid < 7168) { in = W_kc; out = Wt_kc; K = 512;  N = 128;  lx = 2; ly = 4; local = bid - 6144; }
    else if (bid < 7296) { in = W_kr; out = Wt_kr; K = 2048; N = 64;   lx = 1; ly = 6; local = bid - 7168; }
    else                 { in = W_v;  out = Wt_v;  K = 512;  N = 128;  lx = 2; ly = 4; local = bid - 7296; }
    int n0 = (local & ((1 << lx) - 1)) << 5;
    int k0 = ((local >> lx) & ((1 << ly) - 1)) << 5;
    int h  = local >> (lx + ly);
    const float* ip = in + (size_t)h * K * N;
    bf16* op = out + (size_t)h * K * N;
    int tx = threadIdx.x & 31, ty = threadIdx.x >> 5;
#pragma unroll
    for (int i = 0; i < 32; i += 8)
        tile[ty + i][tx] = ip[(size_t)(k0 + ty + i) * N + (n0 + tx)];
    __syncthreads();
#pragma unroll
    for (int i = 0; i < 32; i += 8)
        op[(size_t)(n0 + ty + i) * K + (k0 + tx)] = (bf16)tile[tx][ty + i];
}

// ----------------------------------------------------------------------------
// GEMM core (m97 recipe, BK=64): global_load_lds width-16 staging into
// XOR-swizzled [128][32] LDS slices (8 KB each, 2 k-slices per buffer).
// ----------------------------------------------------------------------------
__device__ __forceinline__ void gld16(const bf16* g, bf16* l) {
    __builtin_amdgcn_global_load_lds(
        (const __attribute__((address_space(1))) void*)g,
        (__attribute__((address_space(3))) void*)l, 16, 0, 0);
}

__device__ __forceinline__ bfx8 frag_ld(const bf16* lds, int row, int quad) {
    int pb = quad ^ ((row >> 1) & 3);
    return *(const bfx8*)(lds + row * 32 + pb * 8);
}

#define SLICE_ 4096   // 128*32 bf16 elems per k-slice

__device__ __forceinline__ void gemm_core(const bf16* __restrict__ A,
                                          const bf16* __restrict__ Bt,
                                          int K, int rowlimB,
                                          floatx4 acc[4][4],
                                          bf16* A_lds, bf16* B_lds) {
    int tid = threadIdx.x, wave = tid >> 6, lane = tid & 63;
    int l15 = lane & 15, quad = lane >> 4;
    int wm = (wave & 1) * 64, wn = (wave >> 1) * 64;
    int ch0 = wave * 2, ch1 = wave * 2 + 1;
    int r0 = ch0 * 16 + (lane >> 2), r1 = ch1 * 16 + (lane >> 2);
    int kb0 = (lane & 3) ^ ((r0 >> 1) & 3), kb1 = (lane & 3) ^ ((r1 >> 1) & 3);
    int rb0 = r0 <= rowlimB ? r0 : rowlimB;
    int rb1 = r1 <= rowlimB ? r1 : rowlimB;
    const bf16* a0 = A + (size_t)r0 * K + kb0 * 8;
    const bf16* a1 = A + (size_t)r1 * K + kb1 * 8;
    const bf16* b0 = Bt + (size_t)rb0 * K + kb0 * 8;
    const bf16* b1 = Bt + (size_t)rb1 * K + kb1 * 8;
    bf16* da0 = A_lds + ch0 * 512;
    bf16* da1 = A_lds + ch1 * 512;
    bf16* db0 = B_lds + ch0 * 512;
    bf16* db1 = B_lds + ch1 * 512;
    for (int k0 = 0; k0 < K; k0 += 64) {
        __syncthreads();
        gld16(a0 + k0, da0);
        gld16(a1 + k0, da1);
        gld16(b0 + k0, db0);
        gld16(b1 + k0, db1);
        gld16(a0 + k0 + 32, da0 + SLICE_);
        gld16(a1 + k0 + 32, da1 + SLICE_);
        gld16(b0 + k0 + 32, db0 + SLICE_);
        gld16(b1 + k0 + 32, db1 + SLICE_);
        __syncthreads();
#pragma unroll
        for (int sl = 0; sl < 2; ++sl) {
            const bf16* As = A_lds + sl * SLICE_;
            const bf16* Bs = B_lds + sl * SLICE_;
            bfx8 a[4], b[4];
#pragma unroll
            for (int t = 0; t < 4; ++t) a[t] = frag_ld(As, wm + t * 16 + l15, quad);
#pragma unroll
            for (int t = 0; t < 4; ++t) b[t] = frag_ld(Bs, wn + t * 16 + l15, quad);
#pragma unroll
            for (int mt = 0; mt < 4; ++mt)
#pragma unroll
                for (int nt = 0; nt < 4; ++nt)
                    acc[mt][nt] = __builtin_amdgcn_mfma_f32_16x16x32_bf16(
                        a[mt], b[nt], acc[mt][nt], 0, 0, 0);
        }
    }
}

// G1: xb -> {c, cp, k_r} (bf16). grid (13, 32) = 416 wg, XCD chunk 52.
__global__ __launch_bounds__(256, 3) void k_gemm1(
    const bf16* __restrict__ xb, const bf16* __restrict__ Wt_c,
    const bf16* __restrict__ Wt_cp, const bf16* __restrict__ Wt_kr,
    bf16* __restrict__ c_ws, bf16* __restrict__ cp_ws, bf16* __restrict__ kr_ws) {
    __shared__ __attribute__((aligned(16))) bf16 A_lds[2 * SLICE_];
    __shared__ __attribute__((aligned(16))) bf16 B_lds[2 * SLICE_];
    int hw = blockIdx.x + 13 * blockIdx.y;
    int virt = (hw & 7) * 52 + (hw >> 3);      // bijective: 416 = 8*52
    int bx = virt % 13, by = virt / 13;
    const bf16* Bt; bf16* outp; int ldc, col0, rowlim;
    if (bx < 4)       { Bt = Wt_c  + (size_t)bx * 128 * DIM_;       outp = c_ws;  ldc = DC_;  col0 = bx * 128;       rowlim = 127; }
    else if (bx < 12) { Bt = Wt_cp + (size_t)(bx - 4) * 128 * DIM_; outp = cp_ws; ldc = DCP_; col0 = (bx - 4) * 128; rowlim = 127; }
    else              { Bt = Wt_kr;                                  outp = kr_ws; ldc = DR_;  col0 = 0;              rowlim = 63;  }
    floatx4 acc[4][4];
#pragma unroll
    for (int i = 0; i < 4; ++i)
#pragma unroll
        for (int j = 0; j < 4; ++j) acc[i][j] = (floatx4){0.f, 0.f, 0.f, 0.f};
    gemm_core(xb + (size_t)by * 128 * DIM_, Bt, DIM_, rowlim, acc, A_lds, B_lds);
    int tid = threadIdx.x, wave = tid >> 6, lane = tid & 63;
    int l15 = lane & 15, quad = lane >> 4;
    int wm = (wave & 1) * 64, wn = (wave >> 1) * 64;
#pragma unroll
    for (int mt = 0; mt < 4; ++mt)
#pragma unroll
        for (int nt = 0; nt < 4; ++nt) {
            int n = wn + nt * 16 + l15;
            if (n > rowlim) continue;
#pragma unroll
            for (int r = 0; r < 4; ++r) {
                int m = by * 128 + wm + mt * 16 + quad * 4 + r;
                outp[(size_t)m * ldc + col0 + n] = (bf16)acc[mt][nt][r];
            }
        }
}

// G2+G3 merged, per-XCD PROPORTIONAL mix (v11 regression fix): each XCD c
// gets 96 G2 blocks (hz = c) + 128 G3 blocks (h = 2c, 2c+1) -> balanced
// iter-load per XCD (96*16 + 128*8 = 2560) and weight L2 locality.
__global__ __launch_bounds__(256, 3) void k_gemm23(
    const bf16* __restrict__ cp_ws, const bf16* __restrict__ c_ws,
    const bf16* __restrict__ Wt_qc, const bf16* __restrict__ Wt_qr,
    const bf16* __restrict__ Wt_kc, const bf16* __restrict__ Wt_v,
    bf16* __restrict__ q_ws, bf16* __restrict__ kc_ws, bf16* __restrict__ vt_ws) {
    __shared__ __attribute__((aligned(16))) bf16 A_lds[2 * SLICE_];
    __shared__ __attribute__((aligned(16))) bf16 B_lds[2 * SLICE_];
    int hw = blockIdx.x;
    int c = hw & 7, idx = hw >> 3;             // XCD id, 0..223 within XCD
    int tid = threadIdx.x, wave = tid >> 6, lane = tid & 63;
    int l15 = lane & 15, quad = lane >> 4;
    int wm = (wave & 1) * 64, wn = (wave >> 1) * 64;
    floatx4 acc[4][4];
#pragma unroll
    for (int i = 0; i < 4; ++i)
#pragma unroll
        for (int j = 0; j < 4; ++j) acc[i][j] = (floatx4){0.f, 0.f, 0.f, 0.f};
    if (idx < 96) {     // ---- G2: virt = c*96 + idx ----
        int virt = c * 96 + idx;
        int bx = virt % 3, by = (virt / 3) & 31, hz = c;
        const bf16* Bt;
        if (bx < 2) Bt = Wt_qc + (size_t)(hz * 2 + bx) * DK_ * DCP_;
        else        Bt = Wt_qr + (size_t)hz * 128 * DCP_;
        gemm_core(cp_ws + (size_t)by * 128 * DCP_, Bt, DCP_, 127, acc, A_lds, B_lds);
#pragma unroll
        for (int mt = 0; mt < 4; ++mt)
#pragma unroll
            for (int nt = 0; nt < 4; ++nt) {
                int n = wn + nt * 16 + l15;
                int h, col;
                if (bx < 2) { h = hz * 2 + bx;        col = n; }
                else        { h = hz * 2 + (n >> 6);  col = 128 + (n & 63); }
#pragma unroll
                for (int r = 0; r < 4; ++r) {
                    int m = by * 128 + wm + mt * 16 + quad * 4 + r;
                    int b = m >> 11, s = m & 2047;
                    q_ws[(((size_t)b * H_ + h) * S_ + s) * DQK_ + col] =
                        (bf16)(acc[mt][nt][r] * C1_);
                }
            }
    } else {            // ---- G3: v2 = c*128 + (idx - 96) ----
        int v2 = c * 128 + (idx - 96);
        int bx = v2 & 1, by = (v2 >> 1) & 31, h = v2 >> 6;
        const bf16* Bt = (bx == 0) ? (Wt_kc + (size_t)h * DK_ * DC_)
                                   : (Wt_v  + (size_t)h * DV_ * DC_);
        gemm_core(c_ws + (size_t)by * 128 * DC_, Bt, DC_, 127, acc, A_lds, B_lds);
#pragma unroll
        for (int mt = 0; mt < 4; ++mt)
#pragma unroll
            for (int nt = 0; nt < 4; ++nt) {
                int n = wn + nt * 16 + l15;
                if (bx == 0) {
#pragma unroll
                    for (int r = 0; r < 4; ++r) {
                        int m = by * 128 + wm + mt * 16 + quad * 4 + r;
                        int b = m >> 11, s = m & 2047;
                        kc_ws[(((size_t)b * H_ + h) * S_ + s) * DK_ + n] = (bf16)acc[mt][nt][r];
                    }
                } else {
                    int m0 = by * 128 + wm + mt * 16 + quad * 4;
                    int b = m0 >> 11, s = m0 & 2047;
                    bfx4 pack;
#pragma unroll
                    for (int r = 0; r < 4; ++r) pack[r] = (bf16)acc[mt][nt][r];
                    *(bfx4*)(&vt_ws[(((size_t)b * H_ + h) * DV_ + n) * S_ + s]) = pack;
                }
            }
    }
}

// ----------------------------------------------------------------------------
// Flash attention v12 = v11 (conflict-free swizzled slices, 79.6 us) with
// 2x2 wave re-tiling. v11 PMC closed the books: LDS-pipe time ~= kernel time
// (168 b128 reads/block-iter). Re-tile: wave (rh=w&1, ch=w>>1) computes the
// 32x32 score quadrant (rows rh*32, cols ch*32) and O rows rh*32 x cols
// ch*64 -> per-wave reads drop 42 -> 24 b128/iter (K 24->12: only its
// col-half; P 2->2; V 16->8), same MFMA count, proven 16x16 layouts.
// P is now cross-wave (PV reads sibling's col-half) -> one extra barrier
// between P-write and PV. qf doubles to 12 frags (+24 VGPR): launch_bounds
// (256,1) lifts the cap to 256 (no spill); residency is grid-limited at
// 2 blocks/CU (512 wg / 256 CU) so the cap change costs nothing.
// OUTPUT FLOAT32. grid (16, 32)
// ----------------------------------------------------------------------------
__global__ __launch_bounds__(256, 1) void k_attn(
    const bf16* __restrict__ q_ws, const bf16* __restrict__ kc_ws,
    const bf16* __restrict__ kr_ws, const bf16* __restrict__ vt_ws,
    float* __restrict__ out) {
    __shared__ __attribute__((aligned(16))) bf16 K_lds[6 * 2048];   // 24 KB
    __shared__ __attribute__((aligned(16))) bf16 V_lds[2 * 4096];   // 16 KB
    __shared__ __attribute__((aligned(16))) bf16 P_lds[2 * 2048];   //  8 KB
    int hw = blockIdx.x + 16 * blockIdx.y;
    int virt = (hw & 7) * 64 + (hw >> 3);      // bijective: 512 = 8*64
    int p = virt & 15;
    int bh = virt >> 4, b = bh >> 4, h = bh & 15;
    int tid = threadIdx.x, wave = tid >> 6, lane = tid & 63;
    int l15 = lane & 15, quad = lane >> 4;
    int rh = wave & 1, ch = wave >> 1;         // row-half, col-half

    // constant ones B-fragment: B[k][n] = 1 iff n==0  (row-sum column)
    bf16 ov = (bf16)(l15 == 0 ? 1.f : 0.f);
    bfx8 ones8 = {ov, ov, ov, ov, ov, ov, ov, ov};

    // dest-linear staging roles: lane writes K_lds/V_lds at tid*8 + slice*2048.
    // Inverse map gives the swizzled global source column.
    int rowk = tid >> 2;                        // 0..63
    int kb   = (tid & 3) ^ ((tid >> 3) & 3);    // XOR swizzle in global col
    const bf16* kcp[4]; const bf16* krp[2]; const bf16* vp[4];
#pragma unroll
    for (int j = 0; j < 4; ++j)
        kcp[j] = kc_ws + ((size_t)bh * S_ + rowk) * DK_ + j * 32 + kb * 8;
#pragma unroll
    for (int j = 0; j < 2; ++j)
        krp[j] = kr_ws + ((size_t)b * S_ + rowk) * DR_ + j * 32 + kb * 8;
#pragma unroll
    for (int j = 0; j < 4; ++j)   // V slice rows = v dim: (j&1)*64 + rowk; col kv = (j>>1)*32
        vp[j] = vt_ws + ((size_t)bh * DV_ + (j & 1) * 64 + rowk) * S_ + (j >> 1) * 32 + kb * 8;
    bf16* kdst = K_lds + (size_t)tid * 8;
    bf16* vdst = V_lds + (size_t)tid * 8;

    for (int ph = 0; ph < 2; ++ph) {
        int qt = ph ? p : 31 - p;
        int q0 = qt * 64, ntiles = qt + 1;

        // Q fragments: this wave's 32 rows (2 sub-tiles of 16), all 192 dims
        bfx8 qf[2][6];
#pragma unroll
        for (int rt = 0; rt < 2; ++rt) {
            const bf16* qrow =
                q_ws + ((size_t)bh * S_ + q0 + rh * 32 + rt * 16 + l15) * DQK_;
#pragma unroll
            for (int ks = 0; ks < 6; ++ks)
                qf[rt][ks] = *(const bfx8*)(qrow + ks * 32 + quad * 8);
        }

        floatx4 o_acc[2][4], l_acc[2];
#pragma unroll
        for (int rt = 0; rt < 2; ++rt) {
            l_acc[rt] = (floatx4){0.f, 0.f, 0.f, 0.f};
#pragma unroll
            for (int vt = 0; vt < 4; ++vt) o_acc[rt][vt] = (floatx4){0.f, 0.f, 0.f, 0.f};
        }

        // prefetch tile 0 into registers
        bfx8 pk[4], pr[2], pv[4];
#pragma unroll
        for (int j = 0; j < 4; ++j) pk[j] = *(const bfx8*)(kcp[j]);
#pragma unroll
        for (int j = 0; j < 2; ++j) pr[j] = *(const bfx8*)(krp[j]);
#pragma unroll
        for (int j = 0; j < 4; ++j) pv[j] = *(const bfx8*)(vp[j]);

        for (int t = 0; t < ntiles; ++t) {
            __syncthreads();   // prior iteration's LDS reads complete
#pragma unroll
            for (int j = 0; j < 4; ++j) *(bfx8*)(kdst + j * 2048) = pk[j];
#pragma unroll
            for (int j = 0; j < 2; ++j) *(bfx8*)(kdst + (4 + j) * 2048) = pr[j];
#pragma unroll
            for (int j = 0; j < 4; ++j) *(bfx8*)(vdst + j * 2048) = pv[j];
            __syncthreads();   // staging visible
            // issue next tile's global loads (latency hidden under compute)
            if (t + 1 < ntiles) {
                size_t kv1 = (size_t)(t + 1) * 64;
#pragma unroll
                for (int j = 0; j < 4; ++j) pk[j] = *(const bfx8*)(kcp[j] + kv1 * DK_);
#pragma unroll
                for (int j = 0; j < 2; ++j) pr[j] = *(const bfx8*)(krp[j] + kv1 * DR_);
#pragma unroll
                for (int j = 0; j < 4; ++j) pv[j] = *(const bfx8*)(vp[j] + kv1);
            }
            // scores: 32x32 quadrant (rows rh*32, cols ch*32); kf reused over rt
            floatx4 sc[2][2];
#pragma unroll
            for (int rt = 0; rt < 2; ++rt)
#pragma unroll
                for (int ct = 0; ct < 2; ++ct) sc[rt][ct] = (floatx4){0.f, 0.f, 0.f, 0.f};
            __builtin_amdgcn_s_setprio(1);
#pragma unroll
            for (int ks = 0; ks < 6; ++ks)
#pragma unroll
                for (int ct = 0; ct < 2; ++ct) {
                    bfx8 kf = frag_ld(K_lds + ks * 2048, ch * 32 + ct * 16 + l15, quad);
                    sc[0][ct] = __builtin_amdgcn_mfma_f32_16x16x32_bf16(qf[0][ks], kf, sc[0][ct], 0, 0, 0);
                    sc[1][ct] = __builtin_amdgcn_mfma_f32_16x16x32_bf16(qf[1][ks], kf, sc[1][ct], 0, 0, 0);
                }
            __builtin_amdgcn_s_setprio(0);
            if (t == ntiles - 1) {   // diagonal tile causal mask
                int kv0 = t * 64;
#pragma unroll
                for (int rt = 0; rt < 2; ++rt)
#pragma unroll
                    for (int ct = 0; ct < 2; ++ct)
#pragma unroll
                        for (int r = 0; r < 4; ++r) {
                            int n_g = kv0 + ch * 32 + ct * 16 + l15;
                            int q_g = q0 + rh * 32 + rt * 16 + quad * 4 + r;
                            if (n_g > q_g) sc[rt][ct][r] = MASK_VAL;
                        }
            }
            // P = exp2(sc) -> LDS (swizzled slice layout; slice index = ch)
#pragma unroll
            for (int rt = 0; rt < 2; ++rt)
#pragma unroll
                for (int ct = 0; ct < 2; ++ct)
#pragma unroll
                    for (int r = 0; r < 4; ++r) {
                        int prow = rh * 32 + rt * 16 + quad * 4 + r;
                        int pcol = ch * 32 + ct * 16 + l15;
                        P_lds[ch * 2048 + prow * 32 +
                              ((((pcol >> 3) & 3) ^ ((prow >> 1) & 3)) * 8) + (pcol & 7)] =
                            (bf16)exp2f(sc[rt][ct][r]);
                    }
            __syncthreads();   // P is cross-wave: sibling col-half must land
            // O += P @ V (rows rh*32, cols ch*64); l via ones column
            __builtin_amdgcn_s_setprio(1);
#pragma unroll
            for (int ks2 = 0; ks2 < 2; ++ks2) {
                bfx8 pf0 = frag_ld(P_lds + ks2 * 2048, rh * 32 + l15, quad);
                bfx8 pf1 = frag_ld(P_lds + ks2 * 2048, rh * 32 + 16 + l15, quad);
#pragma unroll
                for (int vt = 0; vt < 4; ++vt) {
                    bfx8 vf = frag_ld(V_lds + ks2 * 4096, ch * 64 + vt * 16 + l15, quad);
                    o_acc[0][vt] = __builtin_amdgcn_mfma_f32_16x16x32_bf16(pf0, vf, o_acc[0][vt], 0, 0, 0);
                    o_acc[1][vt] = __builtin_amdgcn_mfma_f32_16x16x32_bf16(pf1, vf, o_acc[1][vt], 0, 0, 0);
                }
                l_acc[0] = __builtin_amdgcn_mfma_f32_16x16x32_bf16(pf0, ones8, l_acc[0], 0, 0, 0);
                l_acc[1] = __builtin_amdgcn_mfma_f32_16x16x32_bf16(pf1, ones8, l_acc[1], 0, 0, 0);
            }
            __builtin_amdgcn_s_setprio(0);
        }
        // epilogue: l in l_acc[rt] col 0 (lanes l15==0); broadcast per quad
#pragma unroll
        for (int rt = 0; rt < 2; ++rt) {
            float rinv[4];
#pragma unroll
            for (int r = 0; r < 4; ++r)
                rinv[r] = 1.f / __shfl(l_acc[rt][r], lane & 48);
#pragma unroll
            for (int vt = 0; vt < 4; ++vt)
#pragma unroll
                for (int r = 0; r < 4; ++r) {
                    int s = q0 + rh * 32 + rt * 16 + quad * 4 + r;
                    int v = ch * 64 + vt * 16 + l15;
                    out[((size_t)b * S_ + s) * (H_ * DV_) + h * DV_ + v] =
                        o_acc[rt][vt][r] * rinv[r];
                }
        }
    }
}

// ----------------------------------------------------------------------------
extern "C" void kernel_launch(void* const* d_in, const int* in_sizes, int n_in,
                              void* d_out, int out_size, void* d_ws, size_t ws_size,
                              hipStream_t stream) {
    const float* x    = (const float*)d_in[0];
    const float* W_c  = (const float*)d_in[1];
    const float* W_cp = (const float*)d_in[2];
    const float* W_qc = (const float*)d_in[3];
    const float* W_qr = (const float*)d_in[4];
    const float* W_kc = (const float*)d_in[5];
    const float* W_kr = (const float*)d_in[6];
    const float* W_v  = (const float*)d_in[7];
    float* out = (float*)d_out;

    // d_out (33.5 MB f32) hosts transient bf16 buffers: c 4.2 + cp 8.4 + xb 16.8
    // = 29.4 MB, all dead before k_attn overwrites out.
    bf16* c_ws  = (bf16*)d_out;
    bf16* cp_ws = c_ws + (size_t)B_ * S_ * DC_;
    bf16* xb    = cp_ws + (size_t)B_ * S_ * DCP_;

    char* ws = (char*)d_ws;
    size_t off = 0;
    auto alloc = [&](size_t elems) { bf16* p = (bf16*)(ws + off); off += elems * sizeof(bf16); return p; };
    bf16* Wt_c  = alloc((size_t)DIM_ * DC_);
    bf16* Wt_cp = alloc((size_t)DIM_ * DCP_);
    bf16* Wt_qc = alloc((size_t)H_ * DCP_ * DK_);
    bf16* Wt_qr = alloc((size_t)H_ * DCP_ * DR_);
    bf16* Wt_kc = alloc((size_t)H_ * DC_ * DK_);
    bf16* Wt_kr = alloc((size_t)DIM_ * DR_);
    bf16* Wt_v  = alloc((size_t)H_ * DC_ * DV_);
    bf16* kr_ws = alloc((size_t)B_ * S_ * DR_);
    bf16* q_ws  = alloc((size_t)B_ * H_ * S_ * DQK_);
    bf16* kc_ws = alloc((size_t)B_ * H_ * S_ * DK_);
    bf16* vt_ws = alloc((size_t)B_ * H_ * DV_ * S_);

    k_prep<<<dim3(12416), 256, 0, stream>>>(
        x, xb, W_c, W_cp, W_qc, W_qr, W_kc, W_kr, W_v,
        Wt_c, Wt_cp, Wt_qc, Wt_qr, Wt_kc, Wt_kr, Wt_v);

    k_gemm1<<<dim3(13, 32), 256, 0, stream>>>(xb, Wt_c, Wt_cp, Wt_kr, c_ws, cp_ws, kr_ws);
    k_gemm23<<<dim3(1792), 256, 0, stream>>>(cp_ws, c_ws, Wt_qc, Wt_qr, Wt_kc, Wt_v,
                                             q_ws, kc_ws, vt_ws);
    k_attn<<<dim3(16, B_ * H_), 256, 0, stream>>>(q_ws, kc_ws, kr_ws, vt_ws, out);
}

// Round 11
// 269.367 us; speedup vs baseline: 1.1763x; 1.1763x over previous
//
#include <hip/hip_runtime.h>
#include <stdint.h>

typedef __bf16 bf16;
typedef __bf16 bfx8 __attribute__((ext_vector_type(8)));
typedef __bf16 bfx4 __attribute__((ext_vector_type(4)));
typedef float floatx4 __attribute__((ext_vector_type(4)));

#define B_ 2
#define S_ 2048
#define DIM_ 2048
#define H_ 16
#define DK_ 128
#define DR_ 64
#define DC_ 512
#define DCP_ 1024
#define DV_ 128
#define DQK_ 192

#define MASK_VAL (-30000.0f)
#define C1_ 0.10411754f   // (1/sqrt(192)) * log2(e), folded into q at G2

// ----------------------------------------------------------------------------
// k_prep: fused x-cast (blocks 0..4095) + all-7-weights transpose+downcast
// (blocks 4096..12415). One launch instead of two.
// ----------------------------------------------------------------------------
__global__ void k_prep(
    const float* __restrict__ x, bf16* __restrict__ xb,
    const float* __restrict__ W_c, const float* __restrict__ W_cp,
    const float* __restrict__ W_qc, const float* __restrict__ W_qr,
    const float* __restrict__ W_kc, const float* __restrict__ W_kr,
    const float* __restrict__ W_v,
    bf16* __restrict__ Wt_c, bf16* __restrict__ Wt_cp,
    bf16* __restrict__ Wt_qc, bf16* __restrict__ Wt_qr,
    bf16* __restrict__ Wt_kc, bf16* __restrict__ Wt_kr,
    bf16* __restrict__ Wt_v) {
    __shared__ float tile[32][33];
    int bid0 = blockIdx.x;
    if (bid0 < 4096) {   // cast: 8.4M elems / 8 per thread
        size_t i = ((size_t)bid0 * 256 + threadIdx.x) * 8;
        float4 a = *(const float4*)(x + i);
        float4 b = *(const float4*)(x + i + 4);
        bfx8 r;
        r[0] = (bf16)a.x; r[1] = (bf16)a.y; r[2] = (bf16)a.z; r[3] = (bf16)a.w;
        r[4] = (bf16)b.x; r[5] = (bf16)b.y; r[6] = (bf16)b.z; r[7] = (bf16)b.w;
        *(bfx8*)(xb + i) = r;
        return;
    }
    int bid = bid0 - 4096;
    const float* in; bf16* out; int K, N, lx, ly, local;
    if (bid < 1024)      { in = W_c;  out = Wt_c;  K = 2048; N = 512;  lx = 4; ly = 6; local = bid; }
    else if (bid < 3072) { in = W_cp; out = Wt_cp; K = 2048; N = 1024; lx = 5; ly = 6; local = bid - 1024; }
    else if (bid < 5120) { in = W_qc; out = Wt_qc; K = 1024; N = 128;  lx = 2; ly = 5; local = bid - 3072; }
    else if (bid < 6144) { in = W_qr; out = Wt_qr; K = 1024; N = 64;   lx = 1; ly = 5; local = bid - 5120; }
    else if (bid < 7168) { in = W_kc; out = Wt_kc; K = 512;  N = 128;  lx = 2; ly = 4; local = bid - 6144; }
    else if (bid < 7296) { in = W_kr; out = Wt_kr; K = 2048; N = 64;   lx = 1; ly = 6; local = bid - 7168; }
    else                 { in = W_v;  out = Wt_v;  K = 512;  N = 128;  lx = 2; ly = 4; local = bid - 7296; }
    int n0 = (local & ((1 << lx) - 1)) << 5;
    int k0 = ((local >> lx) & ((1 << ly) - 1)) << 5;
    int h  = local >> (lx + ly);
    const float* ip = in + (size_t)h * K * N;
    bf16* op = out + (size_t)h * K * N;
    int tx = threadIdx.x & 31, ty = threadIdx.x >> 5;
#pragma unroll
    for (int i = 0; i < 32; i += 8)
        tile[ty + i][tx] = ip[(size_t)(k0 + ty + i) * N + (n0 + tx)];
    __syncthreads();
#pragma unroll
    for (int i = 0; i < 32; i += 8)
        op[(size_t)(n0 + ty + i) * K + (k0 + tx)] = (bf16)tile[tx][ty + i];
}

// ----------------------------------------------------------------------------
// GEMM core (m97 recipe, BK=64): global_load_lds width-16 staging into
// XOR-swizzled [128][32] LDS slices (8 KB each, 2 k-slices per buffer).
// ----------------------------------------------------------------------------
__device__ __forceinline__ void gld16(const bf16* g, bf16* l) {
    __builtin_amdgcn_global_load_lds(
        (const __attribute__((address_space(1))) void*)g,
        (__attribute__((address_space(3))) void*)l, 16, 0, 0);
}

__device__ __forceinline__ bfx8 frag_ld(const bf16* lds, int row, int quad) {
    int pb = quad ^ ((row >> 1) & 3);
    return *(const bfx8*)(lds + row * 32 + pb * 8);
}

#define SLICE_ 4096   // 128*32 bf16 elems per k-slice

__device__ __forceinline__ void gemm_core(const bf16* __restrict__ A,
                                          const bf16* __restrict__ Bt,
                                          int K, int rowlimB,
                                          floatx4 acc[4][4],
                                          bf16* A_lds, bf16* B_lds) {
    int tid = threadIdx.x, wave = tid >> 6, lane = tid & 63;
    int l15 = lane & 15, quad = lane >> 4;
    int wm = (wave & 1) * 64, wn = (wave >> 1) * 64;
    int ch0 = wave * 2, ch1 = wave * 2 + 1;
    int r0 = ch0 * 16 + (lane >> 2), r1 = ch1 * 16 + (lane >> 2);
    int kb0 = (lane & 3) ^ ((r0 >> 1) & 3), kb1 = (lane & 3) ^ ((r1 >> 1) & 3);
    int rb0 = r0 <= rowlimB ? r0 : rowlimB;
    int rb1 = r1 <= rowlimB ? r1 : rowlimB;
    const bf16* a0 = A + (size_t)r0 * K + kb0 * 8;
    const bf16* a1 = A + (size_t)r1 * K + kb1 * 8;
    const bf16* b0 = Bt + (size_t)rb0 * K + kb0 * 8;
    const bf16* b1 = Bt + (size_t)rb1 * K + kb1 * 8;
    bf16* da0 = A_lds + ch0 * 512;
    bf16* da1 = A_lds + ch1 * 512;
    bf16* db0 = B_lds + ch0 * 512;
    bf16* db1 = B_lds + ch1 * 512;
    for (int k0 = 0; k0 < K; k0 += 64) {
        __syncthreads();
        gld16(a0 + k0, da0);
        gld16(a1 + k0, da1);
        gld16(b0 + k0, db0);
        gld16(b1 + k0, db1);
        gld16(a0 + k0 + 32, da0 + SLICE_);
        gld16(a1 + k0 + 32, da1 + SLICE_);
        gld16(b0 + k0 + 32, db0 + SLICE_);
        gld16(b1 + k0 + 32, db1 + SLICE_);
        __syncthreads();
#pragma unroll
        for (int sl = 0; sl < 2; ++sl) {
            const bf16* As = A_lds + sl * SLICE_;
            const bf16* Bs = B_lds + sl * SLICE_;
            bfx8 a[4], b[4];
#pragma unroll
            for (int t = 0; t < 4; ++t) a[t] = frag_ld(As, wm + t * 16 + l15, quad);
#pragma unroll
            for (int t = 0; t < 4; ++t) b[t] = frag_ld(Bs, wn + t * 16 + l15, quad);
#pragma unroll
            for (int mt = 0; mt < 4; ++mt)
#pragma unroll
                for (int nt = 0; nt < 4; ++nt)
                    acc[mt][nt] = __builtin_amdgcn_mfma_f32_16x16x32_bf16(
                        a[mt], b[nt], acc[mt][nt], 0, 0, 0);
        }
    }
}

// G1: xb -> {c, cp, k_r} (bf16). grid (13, 32) = 416 wg, XCD chunk 52.
__global__ __launch_bounds__(256, 3) void k_gemm1(
    const bf16* __restrict__ xb, const bf16* __restrict__ Wt_c,
    const bf16* __restrict__ Wt_cp, const bf16* __restrict__ Wt_kr,
    bf16* __restrict__ c_ws, bf16* __restrict__ cp_ws, bf16* __restrict__ kr_ws) {
    __shared__ __attribute__((aligned(16))) bf16 A_lds[2 * SLICE_];
    __shared__ __attribute__((aligned(16))) bf16 B_lds[2 * SLICE_];
    int hw = blockIdx.x + 13 * blockIdx.y;
    int virt = (hw & 7) * 52 + (hw >> 3);      // bijective: 416 = 8*52
    int bx = virt % 13, by = virt / 13;
    const bf16* Bt; bf16* outp; int ldc, col0, rowlim;
    if (bx < 4)       { Bt = Wt_c  + (size_t)bx * 128 * DIM_;       outp = c_ws;  ldc = DC_;  col0 = bx * 128;       rowlim = 127; }
    else if (bx < 12) { Bt = Wt_cp + (size_t)(bx - 4) * 128 * DIM_; outp = cp_ws; ldc = DCP_; col0 = (bx - 4) * 128; rowlim = 127; }
    else              { Bt = Wt_kr;                                  outp = kr_ws; ldc = DR_;  col0 = 0;              rowlim = 63;  }
    floatx4 acc[4][4];
#pragma unroll
    for (int i = 0; i < 4; ++i)
#pragma unroll
        for (int j = 0; j < 4; ++j) acc[i][j] = (floatx4){0.f, 0.f, 0.f, 0.f};
    gemm_core(xb + (size_t)by * 128 * DIM_, Bt, DIM_, rowlim, acc, A_lds, B_lds);
    int tid = threadIdx.x, wave = tid >> 6, lane = tid & 63;
    int l15 = lane & 15, quad = lane >> 4;
    int wm = (wave & 1) * 64, wn = (wave >> 1) * 64;
#pragma unroll
    for (int mt = 0; mt < 4; ++mt)
#pragma unroll
        for (int nt = 0; nt < 4; ++nt) {
            int n = wn + nt * 16 + l15;
            if (n > rowlim) continue;
#pragma unroll
            for (int r = 0; r < 4; ++r) {
                int m = by * 128 + wm + mt * 16 + quad * 4 + r;
                outp[(size_t)m * ldc + col0 + n] = (bf16)acc[mt][nt][r];
            }
        }
}

// G2+G3 merged, per-XCD PROPORTIONAL mix (measured −21 us vs segregated):
// each XCD c gets 96 G2 blocks (hz = c) + 128 G3 blocks (h = 2c, 2c+1) ->
// balanced iter-load per XCD (96*16 + 128*8 = 2560) and weight L2 locality.
__global__ __launch_bounds__(256, 3) void k_gemm23(
    const bf16* __restrict__ cp_ws, const bf16* __restrict__ c_ws,
    const bf16* __restrict__ Wt_qc, const bf16* __restrict__ Wt_qr,
    const bf16* __restrict__ Wt_kc, const bf16* __restrict__ Wt_v,
    bf16* __restrict__ q_ws, bf16* __restrict__ kc_ws, bf16* __restrict__ vt_ws) {
    __shared__ __attribute__((aligned(16))) bf16 A_lds[2 * SLICE_];
    __shared__ __attribute__((aligned(16))) bf16 B_lds[2 * SLICE_];
    int hw = blockIdx.x;
    int c = hw & 7, idx = hw >> 3;             // XCD id, 0..223 within XCD
    int tid = threadIdx.x, wave = tid >> 6, lane = tid & 63;
    int l15 = lane & 15, quad = lane >> 4;
    int wm = (wave & 1) * 64, wn = (wave >> 1) * 64;
    floatx4 acc[4][4];
#pragma unroll
    for (int i = 0; i < 4; ++i)
#pragma unroll
        for (int j = 0; j < 4; ++j) acc[i][j] = (floatx4){0.f, 0.f, 0.f, 0.f};
    if (idx < 96) {     // ---- G2: virt = c*96 + idx ----
        int virt = c * 96 + idx;
        int bx = virt % 3, by = (virt / 3) & 31, hz = c;
        const bf16* Bt;
        if (bx < 2) Bt = Wt_qc + (size_t)(hz * 2 + bx) * DK_ * DCP_;
        else        Bt = Wt_qr + (size_t)hz * 128 * DCP_;
        gemm_core(cp_ws + (size_t)by * 128 * DCP_, Bt, DCP_, 127, acc, A_lds, B_lds);
#pragma unroll
        for (int mt = 0; mt < 4; ++mt)
#pragma unroll
            for (int nt = 0; nt < 4; ++nt) {
                int n = wn + nt * 16 + l15;
                int h, col;
                if (bx < 2) { h = hz * 2 + bx;        col = n; }
                else        { h = hz * 2 + (n >> 6);  col = 128 + (n & 63); }
#pragma unroll
                for (int r = 0; r < 4; ++r) {
                    int m = by * 128 + wm + mt * 16 + quad * 4 + r;
                    int b = m >> 11, s = m & 2047;
                    q_ws[(((size_t)b * H_ + h) * S_ + s) * DQK_ + col] =
                        (bf16)(acc[mt][nt][r] * C1_);
                }
            }
    } else {            // ---- G3: v2 = c*128 + (idx - 96) ----
        int v2 = c * 128 + (idx - 96);
        int bx = v2 & 1, by = (v2 >> 1) & 31, h = v2 >> 6;
        const bf16* Bt = (bx == 0) ? (Wt_kc + (size_t)h * DK_ * DC_)
                                   : (Wt_v  + (size_t)h * DV_ * DC_);
        gemm_core(c_ws + (size_t)by * 128 * DC_, Bt, DC_, 127, acc, A_lds, B_lds);
#pragma unroll
        for (int mt = 0; mt < 4; ++mt)
#pragma unroll
            for (int nt = 0; nt < 4; ++nt) {
                int n = wn + nt * 16 + l15;
                if (bx == 0) {
#pragma unroll
                    for (int r = 0; r < 4; ++r) {
                        int m = by * 128 + wm + mt * 16 + quad * 4 + r;
                        int b = m >> 11, s = m & 2047;
                        kc_ws[(((size_t)b * H_ + h) * S_ + s) * DK_ + n] = (bf16)acc[mt][nt][r];
                    }
                } else {
                    int m0 = by * 128 + wm + mt * 16 + quad * 4;
                    int b = m0 >> 11, s = m0 & 2047;
                    bfx4 pack;
#pragma unroll
                    for (int r = 0; r < 4; ++r) pack[r] = (bf16)acc[mt][nt][r];
                    *(bfx4*)(&vt_ws[(((size_t)b * H_ + h) * DV_ + n) * S_ + s]) = pack;
                }
            }
    }
}

// ----------------------------------------------------------------------------
// Flash attention v13 = v11 verbatim (measured 79.6 us, conflicts 0).
// v12 lesson: wave-private P is load-bearing -- the 2x2 retile's cross-wave
// P needed a 3rd barrier/iter, serializing QK^T and PV across waves
// (occupancy 19.5 -> 11, dur 123 us) despite reading 43% fewer LDS bytes.
// Structure: paired equal-work blocks (33 iters), XCD chunk swizzle
// (FETCH 202 -> 35 MB), m97 swizzled [rows][32] LDS slices everywhere
// (conflict-free frag_ld; staging dest-linear, XOR in global src col),
// wave-private P, s_setprio around MFMA, ones-column row-sum l.
// OUTPUT FLOAT32. grid (16, 32)
// ----------------------------------------------------------------------------
__global__ __launch_bounds__(256, 2) void k_attn(
    const bf16* __restrict__ q_ws, const bf16* __restrict__ kc_ws,
    const bf16* __restrict__ kr_ws, const bf16* __restrict__ vt_ws,
    float* __restrict__ out) {
    __shared__ __attribute__((aligned(16))) bf16 K_lds[6 * 2048];   // 24 KB
    __shared__ __attribute__((aligned(16))) bf16 V_lds[2 * 4096];   // 16 KB
    __shared__ __attribute__((aligned(16))) bf16 P_lds[2 * 2048];   //  8 KB
    int hw = blockIdx.x + 16 * blockIdx.y;
    int virt = (hw & 7) * 64 + (hw >> 3);      // bijective: 512 = 8*64
    int p = virt & 15;
    int bh = virt >> 4, b = bh >> 4, h = bh & 15;
    int tid = threadIdx.x, wave = tid >> 6, lane = tid & 63;
    int l15 = lane & 15, quad = lane >> 4;

    // constant ones B-fragment: B[k][n] = 1 iff n==0  (row-sum column)
    bf16 ov = (bf16)(l15 == 0 ? 1.f : 0.f);
    bfx8 ones8 = {ov, ov, ov, ov, ov, ov, ov, ov};

    // dest-linear staging roles: lane writes K_lds/V_lds at tid*8 + slice*2048.
    // Inverse map gives the swizzled global source column.
    int rowk = tid >> 2;                        // 0..63
    int kb   = (tid & 3) ^ ((tid >> 3) & 3);    // XOR swizzle in global col
    const bf16* kcp[4]; const bf16* krp[2]; const bf16* vp[4];
#pragma unroll
    for (int j = 0; j < 4; ++j)
        kcp[j] = kc_ws + ((size_t)bh * S_ + rowk) * DK_ + j * 32 + kb * 8;
#pragma unroll
    for (int j = 0; j < 2; ++j)
        krp[j] = kr_ws + ((size_t)b * S_ + rowk) * DR_ + j * 32 + kb * 8;
#pragma unroll
    for (int j = 0; j < 4; ++j)   // V slice rows = v dim: (j&1)*64 + rowk; col kv = (j>>1)*32
        vp[j] = vt_ws + ((size_t)bh * DV_ + (j & 1) * 64 + rowk) * S_ + (j >> 1) * 32 + kb * 8;
    bf16* kdst = K_lds + (size_t)tid * 8;
    bf16* vdst = V_lds + (size_t)tid * 8;

    for (int ph = 0; ph < 2; ++ph) {
        int qt = ph ? p : 31 - p;
        int q0 = qt * 64, ntiles = qt + 1;

        const bf16* qrow = q_ws + ((size_t)bh * S_ + q0 + wave * 16 + l15) * DQK_;
        bfx8 qf[6];
#pragma unroll
        for (int ks = 0; ks < 6; ++ks)
            qf[ks] = *(const bfx8*)(qrow + ks * 32 + quad * 8);

        floatx4 o_acc[9];
#pragma unroll
        for (int vt = 0; vt < 9; ++vt) o_acc[vt] = (floatx4){0.f, 0.f, 0.f, 0.f};

        // prefetch tile 0 into registers
        bfx8 pk[4], pr[2], pv[4];
#pragma unroll
        for (int j = 0; j < 4; ++j) pk[j] = *(const bfx8*)(kcp[j]);
#pragma unroll
        for (int j = 0; j < 2; ++j) pr[j] = *(const bfx8*)(krp[j]);
#pragma unroll
        for (int j = 0; j < 4; ++j) pv[j] = *(const bfx8*)(vp[j]);

        for (int t = 0; t < ntiles; ++t) {
            __syncthreads();   // prior iteration's LDS reads complete
#pragma unroll
            for (int j = 0; j < 4; ++j) *(bfx8*)(kdst + j * 2048) = pk[j];
#pragma unroll
            for (int j = 0; j < 2; ++j) *(bfx8*)(kdst + (4 + j) * 2048) = pr[j];
#pragma unroll
            for (int j = 0; j < 4; ++j) *(bfx8*)(vdst + j * 2048) = pv[j];
            __syncthreads();   // staging visible
            // issue next tile's global loads (latency hidden under compute)
            if (t + 1 < ntiles) {
                size_t kv1 = (size_t)(t + 1) * 64;
#pragma unroll
                for (int j = 0; j < 4; ++j) pk[j] = *(const bfx8*)(kcp[j] + kv1 * DK_);
#pragma unroll
                for (int j = 0; j < 2; ++j) pr[j] = *(const bfx8*)(krp[j] + kv1 * DR_);
#pragma unroll
                for (int j = 0; j < 4; ++j) pv[j] = *(const bfx8*)(vp[j] + kv1);
            }
            // scores (exp2 domain: q pre-scaled by C1)
            floatx4 sc[4];
#pragma unroll
            for (int nt = 0; nt < 4; ++nt) sc[nt] = (floatx4){0.f, 0.f, 0.f, 0.f};
            __builtin_amdgcn_s_setprio(1);
#pragma unroll
            for (int ks = 0; ks < 6; ++ks)
#pragma unroll
                for (int nt = 0; nt < 4; ++nt) {
                    bfx8 kf = frag_ld(K_lds + ks * 2048, nt * 16 + l15, quad);
                    sc[nt] = __builtin_amdgcn_mfma_f32_16x16x32_bf16(qf[ks], kf, sc[nt], 0, 0, 0);
                }
            __builtin_amdgcn_s_setprio(0);
            if (t == ntiles - 1) {   // diagonal tile causal mask
                int kv0 = t * 64;
#pragma unroll
                for (int nt = 0; nt < 4; ++nt)
#pragma unroll
                    for (int r = 0; r < 4; ++r) {
                        int n_g = kv0 + nt * 16 + l15;
                        int q_g = q0 + wave * 16 + quad * 4 + r;
                        if (n_g > q_g) sc[nt][r] = MASK_VAL;
                    }
            }
            // P = exp2(sc) -> LDS (swizzled slice layout; wave-private rows)
#pragma unroll
            for (int nt = 0; nt < 4; ++nt)
#pragma unroll
                for (int r = 0; r < 4; ++r) {
                    int prow = wave * 16 + quad * 4 + r;
                    int pcol = nt * 16 + l15;
                    P_lds[(nt >> 1) * 2048 + prow * 32 +
                          ((((pcol >> 3) & 3) ^ ((prow >> 1) & 3)) * 8) + (pcol & 7)] =
                        (bf16)exp2f(sc[nt][r]);
                }
            // O += P @ V ; tile 8 = ones column -> row sums l
            __builtin_amdgcn_s_setprio(1);
#pragma unroll
            for (int ks2 = 0; ks2 < 2; ++ks2) {
                bfx8 pf = frag_ld(P_lds + ks2 * 2048, wave * 16 + l15, quad);
#pragma unroll
                for (int vt = 0; vt < 8; ++vt) {
                    bfx8 vf = frag_ld(V_lds + ks2 * 4096, vt * 16 + l15, quad);
                    o_acc[vt] = __builtin_amdgcn_mfma_f32_16x16x32_bf16(pf, vf, o_acc[vt], 0, 0, 0);
                }
                o_acc[8] = __builtin_amdgcn_mfma_f32_16x16x32_bf16(pf, ones8, o_acc[8], 0, 0, 0);
            }
            __builtin_amdgcn_s_setprio(0);
        }
        // epilogue: l in o_acc[8] col 0 (lanes l15==0); broadcast per quad
        float rinv[4];
#pragma unroll
        for (int r = 0; r < 4; ++r)
            rinv[r] = 1.f / __shfl(o_acc[8][r], lane & 48);
#pragma unroll
        for (int vt = 0; vt < 8; ++vt)
#pragma unroll
            for (int r = 0; r < 4; ++r) {
                int s = q0 + wave * 16 + quad * 4 + r;
                int v = vt * 16 + l15;
                out[((size_t)b * S_ + s) * (H_ * DV_) + h * DV_ + v] = o_acc[vt][r] * rinv[r];
            }
    }
}

// ----------------------------------------------------------------------------
extern "C" void kernel_launch(void* const* d_in, const int* in_sizes, int n_in,
                              void* d_out, int out_size, void* d_ws, size_t ws_size,
                              hipStream_t stream) {
    const float* x    = (const float*)d_in[0];
    const float* W_c  = (const float*)d_in[1];
    const float* W_cp = (const float*)d_in[2];
    const float* W_qc = (const float*)d_in[3];
    const float* W_qr = (const float*)d_in[4];
    const float* W_kc = (const float*)d_in[5];
    const float* W_kr = (const float*)d_in[6];
    const float* W_v  = (const float*)d_in[7];
    float* out = (float*)d_out;

    // d_out (33.5 MB f32) hosts transient bf16 buffers: c 4.2 + cp 8.4 + xb 16.8
    // = 29.4 MB, all dead before k_attn overwrites out.
    bf16* c_ws  = (bf16*)d_out;
    bf16* cp_ws = c_ws + (size_t)B_ * S_ * DC_;
    bf16* xb    = cp_ws + (size_t)B_ * S_ * DCP_;

    char* ws = (char*)d_ws;
    size_t off = 0;
    auto alloc = [&](size_t elems) { bf16* p = (bf16*)(ws + off); off += elems * sizeof(bf16); return p; };
    bf16* Wt_c  = alloc((size_t)DIM_ * DC_);
    bf16* Wt_cp = alloc((size_t)DIM_ * DCP_);
    bf16* Wt_qc = alloc((size_t)H_ * DCP_ * DK_);
    bf16* Wt_qr = alloc((size_t)H_ * DCP_ * DR_);
    bf16* Wt_kc = alloc((size_t)H_ * DC_ * DK_);
    bf16* Wt_kr = alloc((size_t)DIM_ * DR_);
    bf16* Wt_v  = alloc((size_t)H_ * DC_ * DV_);
    bf16* kr_ws = alloc((size_t)B_ * S_ * DR_);
    bf16* q_ws  = alloc((size_t)B_ * H_ * S_ * DQK_);
    bf16* kc_ws = alloc((size_t)B_ * H_ * S_ * DK_);
    bf16* vt_ws = alloc((size_t)B_ * H_ * DV_ * S_);

    k_prep<<<dim3(12416), 256, 0, stream>>>(
        x, xb, W_c, W_cp, W_qc, W_qr, W_kc, W_kr, W_v,
        Wt_c, Wt_cp, Wt_qc, Wt_qr, Wt_kc, Wt_kr, Wt_v);

    k_gemm1<<<dim3(13, 32), 256, 0, stream>>>(xb, Wt_c, Wt_cp, Wt_kr, c_ws, cp_ws, kr_ws);
    k_gemm23<<<dim3(1792), 256, 0, stream>>>(cp_ws, c_ws, Wt_qc, Wt_qr, Wt_kc, Wt_v,
                                             q_ws, kc_ws, vt_ws);
    k_attn<<<dim3(16, B_ * H_), 256, 0, stream>>>(q_ws, kc_ws, kr_ws, vt_ws, out);
}